// Round 3
// baseline (912.008 us; speedup 1.0000x reference)
//
#include <hip/hip_runtime.h>
#include <hip/hip_bf16.h>

#define LSEQ 384
#define BATCH 32
#define BIGV 1e30f
#define TB_STK 448
#define NN ((size_t)LSEQ * LSEQ)
#define BT 32          // tile size
#define NT 12          // tiles per side
#define PIT 33         // LDS pitch

__device__ __forceinline__ int detect_mmode_wave(const unsigned char* m0, int lane) {
    unsigned char v = m0[lane & 63];
    unsigned long long big = __ballot(v >= 2);
    unsigned long long off = __ballot((((lane & 63) & 3) != 0) && (v != 0));
    return big ? 2 : (off ? 1 : 0);
}
__device__ __forceinline__ bool mask_read(const void* mask, size_t idx, int mmode) {
    if (mmode == 0) return ((const unsigned int*)mask)[idx] != 0;
    if (mmode == 1) return ((const unsigned char*)mask)[idx] != 0;
    return ((const unsigned short*)mask)[idx] != 0;
}
__device__ __forceinline__ void choice_write(void* mask, size_t idx, int c, int mmode) {
    if (mmode == 0) ((unsigned int*)mask)[idx] = (unsigned int)c;
    else if (mmode == 1) ((unsigned char*)mask)[idx] = (unsigned char)c;
    else ((unsigned short*)mask)[idx] = (unsigned short)c;
}

// Fixed-length branchless edge reduction: min over kk in [0,32) of
// rowp[kk] + colp[kk*PIT]. Out-of-range terms are made >= 1e30 by
// BIGV-prefilled lower triangles / pad rows, so they never win or tie
// (real dp values < 1e4) -> results bitwise identical to the ranged
// version. Fully unrolled: all 64 LDS loads issue back-to-back.
__device__ __forceinline__ float edge_min32(const float* rowp, const float* colp) {
    float a0 = BIGV, a1 = BIGV, a2 = BIGV, a3 = BIGV;
    #pragma unroll
    for (int kk = 0; kk < 32; kk += 4) {
        float r0 = rowp[kk], r1 = rowp[kk + 1], r2 = rowp[kk + 2], r3 = rowp[kk + 3];
        const float* cb = colp + kk * PIT;
        float c0 = cb[0], c1 = cb[PIT], c2 = cb[2 * PIT], c3 = cb[3 * PIT];
        a0 = fminf(a0, r0 + c0); a1 = fminf(a1, r1 + c1);
        a2 = fminf(a2, r2 + c2); a3 = fminf(a3, r3 + c3);
    }
    return fminf(fminf(a0, a1), fminf(a2, a3));
}

// ---------- phase 0: one block (1 wave) per diagonal tile ----------
__global__ __launch_bounds__(64) void diag_kernel(
    float* __restrict__ e_pair, const float* __restrict__ e_unp, void* mask)
{
    __shared__ float dT[BT + 1][PIT];   // BIGV-prefilled; row 32 = pad
    __shared__ float epm[BT][PIT];
    __shared__ float s_eunp[BT];

    const int bid = blockIdx.x;
    const int b = bid / NT, t = bid % NT;
    const int lane = threadIdx.x;
    float* dpG = e_pair + (size_t)b * NN;
    const size_t mb = (size_t)b * NN;
    const int mmode = detect_mmode_wave((const unsigned char*)mask, lane);

    for (int z = lane; z < (BT + 1) * PIT; z += 64) ((float*)dT)[z] = BIGV;
    __syncthreads();
    if (lane < BT) {
        int i = t * BT + lane;
        float v = e_unp[b * LSEQ + i];
        s_eunp[lane] = v;
        dT[lane][lane] = v;                            // dp[i][i]
        dpG[(size_t)i * LSEQ + i] = v;
        if (i > 0) dpG[(size_t)i * LSEQ + i - 1] = v;  // mirror
    }
    for (int z = lane; z < BT * BT; z += 64) {         // stage masked energies
        int li = z >> 5, lj = z & 31;
        int i = t * BT + li, j = t * BT + lj;
        bool ok = (lj - li > 4) && mask_read(mask, mb + (size_t)i * LSEQ + j, mmode);
        epm[li][lj] = ok ? dpG[(size_t)i * LSEQ + j] : BIGV;
    }
    __syncthreads();

    const int idx = lane >> 1, h = lane & 1;
    for (int sg = 1; sg < BT; ++sg) {
        const int nc = BT - sg;
        const bool act = idx < nc;
        const int li = idx, lj = idx + sg;
        const int ljc = lj < BT ? lj : BT - 1;         // clamp for inactive lanes
        const int i = t * BT + li, j = t * BT + lj;
        float ev = edge_min32(&dT[li][0], &dT[1][ljc]);
        float e1 = BIGV, opt0 = 0.f, x1 = BIGV, x2 = BIGV;
        if (act) {
            if (h == 0) {
                e1 = ev;                               // includes opt0(kk=li), opt1(kk=lj-1)
                opt0 = dT[li + 1][lj] + s_eunp[li];
            } else {
                x1 = dT[li][lj - 1] + s_eunp[lj];
                float pe = epm[li][lj];
                if (pe < BIGV) x2 = dT[li + 1][lj - 1] + pe;
            }
        }
        float y1 = __shfl_xor(x1, 1), y2 = __shfl_xor(x2, 1);
        if (act && h == 0) {
            float best = fminf(e1, y2);
            int cch = (best == opt0) ? 0 : (best == y1) ? 1
                     : (best == y2 && y2 < BIGV) ? 2 : 3;
            dT[li][lj] = best;
            dpG[(size_t)i * LSEQ + j] = best;
            if (i > 0) dpG[(size_t)j * LSEQ + i - 1] = best;
            choice_write(mask, mb + (size_t)j * LSEQ + i, cch, mmode);
        }
    }
}

// ---------- phase s (1..NT-1): one block (8 waves) per tile (I, I+s).
// Inter-phase dependency = stream-ordered kernel boundary (no barriers).
// Waves 0-7 split staging + far-init over M (stride 8) + merge;
// wave 0 sweeps alone on an unshared SIMD.
__global__ __launch_bounds__(512) void phase_kernel(
    float* __restrict__ e_pair, const float* __restrict__ e_unp, void* mask, int s)
{
    __shared__ float dTI[BT + 1][PIT], dTJ[BT + 1][PIT];  // strict lower + pad = BIGV
    __shared__ float cur[BT + 1][PIT];                    // row 32 = pad BIGV
    __shared__ float epm[BT][PIT];
    __shared__ float part[8][BT][PIT];
    __shared__ float brow[BT], bcol[BT], s_eI[BT], s_eJ[BT];
    __shared__ float bcorn;

    const int nt = NT - s;
    const int bid = blockIdx.x;
    const int b = bid / nt, I = bid % nt, J = I + s;
    const int tid = threadIdx.x, lane = tid & 63, wv = tid >> 6;
    float* dpG = e_pair + (size_t)b * NN;
    const size_t mb = (size_t)b * NN;
    const int mmode = detect_mmode_wave((const unsigned char*)mask, lane);

    // stage the two diagonal tiles; strict lower triangle -> BIGV
    for (int z = tid; z < BT * BT; z += 512) {
        int li = z >> 5, lj = z & 31;
        dTI[li][lj] = (lj >= li) ? dpG[(size_t)(I * BT + li) * LSEQ + I * BT + lj] : BIGV;
        dTJ[li][lj] = (lj >= li) ? dpG[(size_t)(J * BT + li) * LSEQ + J * BT + lj] : BIGV;
    }
    for (int z = tid; z < PIT; z += 512) {             // pad rows
        dTI[BT][z] = BIGV; dTJ[BT][z] = BIGV; cur[BT][z] = BIGV;
    }
    if (tid < BT) {
        brow[tid] = dpG[(size_t)((I + 1) * BT) * LSEQ + J * BT + tid];
        s_eI[tid] = e_unp[b * LSEQ + I * BT + tid];
    } else if (tid < 2 * BT) {
        int q = tid - BT;
        bcol[q] = dpG[(size_t)(I * BT + q) * LSEQ + J * BT - 1];
        s_eJ[q] = e_unp[b * LSEQ + J * BT + q];
    } else if (tid == 2 * BT) {
        bcorn = (s >= 2) ? dpG[(size_t)((I + 1) * BT) * LSEQ + J * BT - 1] : BIGV;
    }
    for (int z = tid; z < BT * BT; z += 512) {         // stage masked energies
        int li = z >> 5, lj = z & 31;
        int i = I * BT + li, j = J * BT + lj;
        bool ok = (j - i > 4) && mask_read(mask, mb + (size_t)i * LSEQ + j, mmode);
        epm[li][lj] = ok ? dpG[(size_t)i * LSEQ + j] : BIGV;
    }

    // far-init: 8-way split over middle tiles M, exact same term set
    if (s == 1) {
        for (int z = tid; z < BT * PIT; z += 512) ((float*)cur)[z] = BIGV;
    } else {
        const int r0 = (lane >> 3) << 2, c0 = (lane & 7) << 2;
        float r16[16];
        #pragma unroll
        for (int z = 0; z < 16; ++z) r16[z] = BIGV;
        for (int M = I + 1 + wv; M < J; M += 8) {
            #pragma unroll
            for (int kq = 0; kq < 8; ++kq) {
                const int k = M * BT + kq * 4;
                float4 a0 = *(const float4*)&dpG[(size_t)(I * BT + r0 + 0) * LSEQ + k];
                float4 a1 = *(const float4*)&dpG[(size_t)(I * BT + r0 + 1) * LSEQ + k];
                float4 a2 = *(const float4*)&dpG[(size_t)(I * BT + r0 + 2) * LSEQ + k];
                float4 a3 = *(const float4*)&dpG[(size_t)(I * BT + r0 + 3) * LSEQ + k];
                float4 b0 = *(const float4*)&dpG[(size_t)(J * BT + c0 + 0) * LSEQ + k];
                float4 b1 = *(const float4*)&dpG[(size_t)(J * BT + c0 + 1) * LSEQ + k];
                float4 b2 = *(const float4*)&dpG[(size_t)(J * BT + c0 + 2) * LSEQ + k];
                float4 b3 = *(const float4*)&dpG[(size_t)(J * BT + c0 + 3) * LSEQ + k];
                #pragma unroll
                for (int ri = 0; ri < 4; ++ri) {
                    float4 av = ri == 0 ? a0 : ri == 1 ? a1 : ri == 2 ? a2 : a3;
                    #pragma unroll
                    for (int ci = 0; ci < 4; ++ci) {
                        float4 bv = ci == 0 ? b0 : ci == 1 ? b1 : ci == 2 ? b2 : b3;
                        float m = fminf(fminf(av.x + bv.x, av.y + bv.y),
                                        fminf(av.z + bv.z, av.w + bv.w));
                        r16[ri * 4 + ci] = fminf(r16[ri * 4 + ci], m);
                    }
                }
            }
        }
        #pragma unroll
        for (int ri = 0; ri < 4; ++ri)
            #pragma unroll
            for (int ci = 0; ci < 4; ++ci)
                part[wv][r0 + ri][c0 + ci] = r16[ri * 4 + ci];
        __syncthreads();
        for (int z = tid; z < BT * BT; z += 512) {
            int li = z >> 5, lj = z & 31;
            float m01 = fminf(part[0][li][lj], part[1][li][lj]);
            float m23 = fminf(part[2][li][lj], part[3][li][lj]);
            float m45 = fminf(part[4][li][lj], part[5][li][lj]);
            float m67 = fminf(part[6][li][lj], part[7][li][lj]);
            cur[li][lj] = fminf(fminf(m01, m23), fminf(m45, m67));
        }
    }
    __syncthreads();
    if (wv != 0) return;   // wave 0 sweeps with an unshared SIMD

    const int idx = lane >> 1, h = lane & 1;
    for (int sg = -(BT - 1); sg <= BT - 1; ++sg) {
        const int asg = sg < 0 ? -sg : sg;
        const int nc = BT - asg;
        const bool act = idx < nc;
        const int li = (sg >= 0) ? idx : idx - sg;
        const int lj = li + sg;
        const int lic = li < BT ? li : BT - 1;         // clamp for inactive lanes
        const int ljc = (lj < BT ? (lj >= 0 ? lj : 0) : BT - 1);
        const int i = I * BT + li, j = J * BT + lj;
        // h0: real kk in [li,31): dTI[li][kk] + cur[kk+1][lj]
        // h1: real kk in [0,lj):  cur[li][kk] + dTJ[kk+1][lj]
        const float* rowp = (h == 0) ? &dTI[lic][0] : &cur[lic][0];
        const float* colp = (h == 0) ? &cur[1][ljc] : &dTJ[1][ljc];
        float ev = edge_min32(rowp, colp);
        float e1 = BIGV, opt0 = 0.f, farv = BIGV;
        float x0 = BIGV, x1 = BIGV, x2 = BIGV;
        if (act) {
            if (h == 0) {
                e1 = fminf(ev, dTI[li][BT - 1] + brow[lj]);
                opt0 = ((li + 1 < BT) ? cur[li + 1][lj] : brow[lj]) + s_eI[li];
                farv = cur[li][lj];
            } else {
                x0 = ev;
                x1 = ((lj >= 1) ? cur[li][lj - 1] : bcol[li]) + s_eJ[lj];
                float pe = epm[li][lj];
                if (pe < BIGV) {
                    float inner = (li + 1 < BT)
                        ? ((lj >= 1) ? cur[li + 1][lj - 1] : bcol[li + 1])
                        : ((lj >= 1) ? brow[lj - 1] : bcorn);
                    x2 = inner + pe;
                }
            }
        }
        float y0 = __shfl_xor(x0, 1), y1 = __shfl_xor(x1, 1), y2 = __shfl_xor(x2, 1);
        if (act && h == 0) {
            float best = fminf(fminf(fminf(e1, y0), farv), y2);
            int cch = (best == opt0) ? 0 : (best == y1) ? 1
                     : (best == y2 && y2 < BIGV) ? 2 : 3;
            cur[li][lj] = best;
            dpG[(size_t)i * LSEQ + j] = best;
            if (i > 0) dpG[(size_t)j * LSEQ + i - 1] = best;
            choice_write(mask, mb + (size_t)j * LSEQ + i, cch, mmode);
        }
    }
}

// Traceback: 8 waves stage the choice matrix into LDS (8x the outstanding
// loads vs 1 wave -> staging goes from ~140us latency-bound to ~10us),
// then wave 0 traverses barrier-free with the interval cached in regs.
__global__ __launch_bounds__(512) void tb_kernel(
    const float* __restrict__ e_pair, const void* mask, float* __restrict__ out)
{
    const int b = blockIdx.x;
    const int tid = threadIdx.x;
    const int lane = tid & 63, wv = tid >> 6;
    const float* dp = e_pair + (size_t)b * NN;
    const size_t mb = (size_t)b * NN;
    const int mmode = detect_mmode_wave((const unsigned char*)mask, lane);

    __shared__ __align__(16) unsigned char ch[LSEQ * LSEQ];   // 147456 B
    __shared__ short res[LSEQ];
    __shared__ int st[TB_STK];

    if (mmode == 1) {
        const uint4* src = (const uint4*)((const unsigned char*)mask + mb);
        for (int z = tid; z < (int)(NN / 16); z += 512) ((uint4*)ch)[z] = src[z];
    } else if (mmode == 2) {
        const uint4* src = (const uint4*)((const unsigned char*)mask + mb * 2);
        for (int z = tid; z < (int)(NN / 8); z += 512) {
            uint4 v = src[z];
            unsigned int lo = (v.x & 0xFFu) | (((v.x >> 16) & 0xFFu) << 8)
                            | ((v.y & 0xFFu) << 16) | (((v.y >> 16) & 0xFFu) << 24);
            unsigned int hi = (v.z & 0xFFu) | (((v.z >> 16) & 0xFFu) << 8)
                            | ((v.w & 0xFFu) << 16) | (((v.w >> 16) & 0xFFu) << 24);
            ((unsigned int*)ch)[z * 2] = lo;
            ((unsigned int*)ch)[z * 2 + 1] = hi;
        }
    } else {
        const uint4* src = (const uint4*)((const unsigned char*)mask + mb * 4);
        for (int z = tid; z < (int)(NN / 4); z += 512) {
            uint4 v = src[z];
            ((unsigned int*)ch)[z] = (v.x & 0xFFu) | ((v.y & 0xFFu) << 8)
                                   | ((v.z & 0xFFu) << 16) | ((v.w & 0xFFu) << 24);
        }
    }
    for (int l = tid; l < LSEQ; l += 512) res[l] = -1;
    __syncthreads();
    if (wv != 0) return;   // wave 0 traverses alone

    int sp = 0;
    int ci = 0, cj = LSEQ - 1;
    int have = 1;
    for (int iter = 0; iter < 8192; ++iter) {
        if (!have) {
            if (sp == 0) break;
            --sp;
            int pk = st[sp];
            ci = pk >> 16; cj = pk & 0xFFFF;
        }
        have = 0;
        if (ci >= cj) continue;
        int c = ch[(size_t)cj * LSEQ + ci];
        if (c == 0) { ++ci; have = 1; }
        else if (c == 1) { --cj; have = 1; }
        else if (c == 2) {
            res[ci] = (short)cj; res[cj] = (short)ci;
            if (ci + 1 <= cj - 1) { ++ci; --cj; have = 1; }
        } else {
            const int d = cj - ci;
            const float* rowi = dp + (size_t)ci * LSEQ;
            const float* mrow = dp + (size_t)cj * LSEQ;
            float bv = BIGV; int bt = d;
            for (int t = lane; t < d; t += 64) {
                float cc = rowi[ci + t] + mrow[ci + t];
                if (cc < bv || (cc == bv && t < bt)) { bv = cc; bt = t; }
            }
            for (int m = 32; m > 0; m >>= 1) {
                float ov = __shfl_xor(bv, m, 64);
                int   ot = __shfl_xor(bt, m, 64);
                if (ov < bv || (ov == bv && ot < bt)) { bv = ov; bt = ot; }
            }
            int k = ci + bt;
            if (sp < TB_STK - 1) { st[sp] = ((k + 1) << 16) | cj; ++sp; }
            cj = k; have = 1;   // process (ci, k) next
        }
    }

    for (int l = lane; l < LSEQ; l += 64)
        out[b * LSEQ + l] = (float)res[l];
    if (lane == 0)
        out[BATCH * LSEQ + b] = dp[LSEQ - 1];
}

extern "C" void kernel_launch(void* const* d_in, const int* in_sizes, int n_in,
                              void* d_out, int out_size, void* d_ws, size_t ws_size,
                              hipStream_t stream) {
    float* e_pair = (float*)d_in[0];
    const float* e_unp = (const float*)d_in[1];
    void* mask = d_in[2];
    (void)d_ws; (void)ws_size;

    diag_kernel<<<BATCH * NT, 64, 0, stream>>>(e_pair, e_unp, mask);
    for (int s = 1; s < NT; ++s)
        phase_kernel<<<BATCH * (NT - s), 512, 0, stream>>>(e_pair, e_unp, mask, s);
    tb_kernel<<<BATCH, 512, 0, stream>>>(e_pair, mask, (float*)d_out);
}

// Round 5
// 884.805 us; speedup vs baseline: 1.0307x; 1.0307x over previous
//
#include <hip/hip_runtime.h>

#define LSEQ 384
#define BATCH 32
#define BIGV 1e30f
#define TB_STK 448
#define NN ((size_t)LSEQ * LSEQ)
#define BT 32          // tile size
#define NT 12          // tiles per side
#define PIT 33         // LDS pitch
#define NJOBS (BATCH * NT)   // 384 row-jobs
#define WS_CNT_BASE 8  // ws[8 + b*16 + s] = #tiles of (batch b, phase s) done
#define SPIN_CAP (1 << 21)   // bounded spin: bail -> wrong answer, never a hang

__device__ __forceinline__ int detect_mmode_wave(const unsigned char* m0, int lane) {
    unsigned char v = m0[lane & 63];
    unsigned long long big = __ballot(v >= 2);
    unsigned long long off = __ballot((((lane & 63) & 3) != 0) && (v != 0));
    return big ? 2 : (off ? 1 : 0);
}
__device__ __forceinline__ bool mask_read(const void* mask, size_t idx, int mmode) {
    if (mmode == 0) return ((const unsigned int*)mask)[idx] != 0;
    if (mmode == 1) return ((const unsigned char*)mask)[idx] != 0;
    return ((const unsigned short*)mask)[idx] != 0;
}
// Choice writes: scoped atomic stores (device scope) -> performed dword/byte-
// granular at the MALL coherence point. Plain stores would false-share cache
// lines between tiles of different phases running on different XCDs.
__device__ __forceinline__ void choice_write_rel(void* mask, size_t idx, int c, int mmode) {
    if (mmode == 0)
        __hip_atomic_store((unsigned int*)mask + idx, (unsigned int)c,
                           __ATOMIC_RELAXED, __HIP_MEMORY_SCOPE_AGENT);
    else if (mmode == 1)
        __hip_atomic_store((unsigned char*)mask + idx, (unsigned char)c,
                           __ATOMIC_RELAXED, __HIP_MEMORY_SCOPE_AGENT);
    else
        __hip_atomic_store((unsigned short*)mask + idx, (unsigned short)c,
                           __ATOMIC_RELAXED, __HIP_MEMORY_SCOPE_AGENT);
}
__device__ __forceinline__ float aload(const float* p) {
    return __hip_atomic_load((float*)p, __ATOMIC_RELAXED, __HIP_MEMORY_SCOPE_AGENT);
}
__device__ __forceinline__ float4 aload4(const float* p) {
    union { unsigned long long u[2]; float4 f; } r;
    unsigned long long* q = (unsigned long long*)p;
    r.u[0] = __hip_atomic_load(q, __ATOMIC_RELAXED, __HIP_MEMORY_SCOPE_AGENT);
    r.u[1] = __hip_atomic_load(q + 1, __ATOMIC_RELAXED, __HIP_MEMORY_SCOPE_AGENT);
    return r.f;
}
__device__ __forceinline__ void astore(float* p, float v) {
    __hip_atomic_store(p, v, __ATOMIC_RELAXED, __HIP_MEMORY_SCOPE_AGENT);
}

// Fixed-length branchless edge reduction (R2-verified): min over kk in [0,32)
// of rowp[kk] + colp[kk*PIT]; out-of-range terms >= 1e30 via BIGV prefill ->
// never win or tie -> bitwise identical to the ranged version.
__device__ __forceinline__ float edge_min32(const float* rowp, const float* colp) {
    float a0 = BIGV, a1 = BIGV, a2 = BIGV, a3 = BIGV;
    #pragma unroll
    for (int kk = 0; kk < 32; kk += 4) {
        float r0 = rowp[kk], r1 = rowp[kk + 1], r2 = rowp[kk + 2], r3 = rowp[kk + 3];
        const float* cb = colp + kk * PIT;
        float c0 = cb[0], c1 = cb[PIT], c2 = cb[2 * PIT], c3 = cb[3 * PIT];
        a0 = fminf(a0, r0 + c0); a1 = fminf(a1, r1 + c1);
        a2 = fminf(a2, r2 + c2); a3 = fminf(a3, r3 + c3);
    }
    return fminf(fminf(a0, a1), fminf(a2, a3));
}

__global__ void init_ws(unsigned int* __restrict__ ws) {
    for (int z = threadIdx.x; z < WS_CNT_BASE + BATCH * 16; z += 256) ws[z] = 0;
}

// Persistent row-worker DP. Worker (b,I) = one block (4 waves, 256 thr),
// pulled from a b-major job queue (resident prefix always contains whole
// batches -> progress guaranteed for >=12 resident blocks). It computes
// tiles (I,I), (I,I+1), ..., (I,NT-1) sequentially, keeping ALL its row
// tiles in LDS (A-panels + bcol never re-read from global). Cross-worker
// dp traffic is sc1 relaxed-agent (MALL coherence point); release =
// vmcnt-drain + barrier + per-(b,phase) counter inc; acquire = bounded
// counter poll + barrier. Tile math is the R2-verified version verbatim.
__global__ __launch_bounds__(256) void dp_rows(
    float* __restrict__ e_pair, const float* __restrict__ e_unp,
    void* mask, unsigned int* __restrict__ ws)
{
    __shared__ float rowT[NT][BT + 1][PIT];   // 52272 B: own row tiles (+pad row)
    __shared__ float dTJ[BT + 1][PIT];        // 4356 B
    __shared__ float epm[BT][PIT];            // 4224 B
    __shared__ float brow[BT], s_eI[BT], s_eJ[BT];
    __shared__ float bcorn_s;
    __shared__ unsigned int s_job;

    const int tid = threadIdx.x, lane = tid & 63, wv = tid >> 6;
    const int mmode = detect_mmode_wave((const unsigned char*)mask, lane);

    for (;;) {
        if (tid == 0)
            s_job = __hip_atomic_fetch_add(&ws[0], 1u, __ATOMIC_RELAXED,
                                           __HIP_MEMORY_SCOPE_AGENT);
        __syncthreads();
        const unsigned int job = s_job;
        if (job >= NJOBS) return;
        const int b = (int)(job / NT);        // b-major
        const int I = (int)(job % NT);
        float* dpG = e_pair + (size_t)b * NN;
        const size_t mb = (size_t)b * NN;
        unsigned int* cnt = ws + WS_CNT_BASE + b * 16;

        // per-job init: all row-tile slots + dTJ = BIGV (lower tri & pads), s_eI
        for (int z = tid; z < NT * (BT + 1) * PIT; z += 256) ((float*)rowT)[z] = BIGV;
        for (int z = tid; z < (BT + 1) * PIT; z += 256) ((float*)dTJ)[z] = BIGV;
        if (tid < BT) s_eI[tid] = e_unp[b * LSEQ + I * BT + tid];
        __syncthreads();

        // ---------------- phase 0: diagonal tile (I,I) -> rowT[0] ----------------
        if (tid < BT) {
            int i = I * BT + tid;
            float v = s_eI[tid];
            rowT[0][tid][tid] = v;                        // dp[i][i]
            astore(&dpG[(size_t)i * LSEQ + i], v);
            if (i > 0) astore(&dpG[(size_t)i * LSEQ + i - 1], v);   // mirror
        }
        for (int z = tid; z < BT * BT; z += 256) {        // masked energies (own tile)
            int li = z >> 5, lj = z & 31;
            int i = I * BT + li, j = I * BT + lj;
            bool ok = (lj - li > 4) && mask_read(mask, mb + (size_t)i * LSEQ + j, mmode);
            epm[li][lj] = ok ? dpG[(size_t)i * LSEQ + j] : BIGV;
        }
        __syncthreads();
        if (wv == 0) {
            const int idx = lane >> 1, h = lane & 1;
            for (int sg = 1; sg < BT; ++sg) {
                const int nc = BT - sg;
                const bool act = idx < nc;
                const int li = idx, lj = idx + sg;
                const int ljc = lj < BT ? lj : BT - 1;
                const int i = I * BT + li, j = I * BT + lj;
                float ev = edge_min32(&rowT[0][li][0], &rowT[0][1][ljc]);
                float e1 = BIGV, opt0 = 0.f, x1 = BIGV, x2 = BIGV;
                if (act) {
                    if (h == 0) {
                        e1 = ev;                          // includes opt0(kk=li), opt1(kk=lj-1)
                        opt0 = rowT[0][li + 1][lj] + s_eI[li];
                    } else {
                        x1 = rowT[0][li][lj - 1] + s_eI[lj];
                        float pe = epm[li][lj];
                        if (pe < BIGV) x2 = rowT[0][li + 1][lj - 1] + pe;
                    }
                }
                float y1 = __shfl_xor(x1, 1), y2 = __shfl_xor(x2, 1);
                if (act && h == 0) {
                    float best = fminf(e1, y2);
                    int cch = (best == opt0) ? 0 : (best == y1) ? 1
                             : (best == y2 && y2 < BIGV) ? 2 : 3;
                    rowT[0][li][lj] = best;
                    astore(&dpG[(size_t)i * LSEQ + j], best);
                    if (i > 0) astore(&dpG[(size_t)j * LSEQ + i - 1], best);
                    choice_write_rel(mask, mb + (size_t)j * LSEQ + i, cch, mmode);
                }
            }
        }
        asm volatile("s_waitcnt vmcnt(0)" ::: "memory");
        __syncthreads();
        if (tid == 0)
            __hip_atomic_fetch_add(&cnt[0], 1u, __ATOMIC_RELAXED,
                                   __HIP_MEMORY_SCOPE_AGENT);

        // ---------------- phases s = 1 .. NT-1-I: tile (I, I+s) ----------------
        for (int s = 1; s <= NT - 1 - I; ++s) {
            const int J = I + s;
            float (*cur)[PIT] = rowT[s];
            float (*prv)[PIT] = rowT[s - 1];

            if (tid == 0) {                   // wait own batch's phase s-1 complete
                const unsigned int need = (unsigned int)(NT - (s - 1));
                int spin = 0;
                while (__hip_atomic_load(&cnt[s - 1], __ATOMIC_RELAXED,
                                         __HIP_MEMORY_SCOPE_AGENT) < need) {
                    __builtin_amdgcn_s_sleep(8);
                    if (++spin > SPIN_CAP) break;        // bail, don't hang
                }
            }
            __syncthreads();                  // acquire

            // stage dTJ (upper tri; lower stays BIGV), brow, s_eJ, bcorn, epm
            for (int z = tid; z < BT * BT; z += 256) {
                int li = z >> 5, lj = z & 31;
                dTJ[li][lj] = (lj >= li)
                    ? aload(&dpG[(size_t)(J * BT + li) * LSEQ + J * BT + lj]) : BIGV;
            }
            if (tid < BT) {
                brow[tid] = aload(&dpG[(size_t)((I + 1) * BT) * LSEQ + J * BT + tid]);
                s_eJ[tid] = e_unp[b * LSEQ + J * BT + tid];
            } else if (tid == BT) {
                bcorn_s = (s >= 2)
                    ? aload(&dpG[(size_t)((I + 1) * BT) * LSEQ + J * BT - 1]) : BIGV;
            }
            for (int z = tid; z < BT * BT; z += 256) {    // masked energies (own tile)
                int li = z >> 5, lj = z & 31;
                int i = I * BT + li, j = J * BT + lj;
                bool ok = (j - i > 4) && mask_read(mask, mb + (size_t)i * LSEQ + j, mmode);
                epm[li][lj] = ok ? dpG[(size_t)i * LSEQ + j] : BIGV;
            }

            // far-init into cur: A-panels from LDS rowT (own), B-panels global sc1
            if (s == 1) {
                for (int z = tid; z < BT * PIT; z += 256) ((float*)cur)[z] = BIGV;
                __syncthreads();
            } else {
                const int r0 = (lane >> 3) << 2, c0 = (lane & 7) << 2;
                float r16[16];
                #pragma unroll
                for (int z = 0; z < 16; ++z) r16[z] = BIGV;
                for (int m = 1 + wv; m < s; m += 4) {
                    float (*A)[PIT] = rowT[m];
                    const int kg = (I + m) * BT;
                    #pragma unroll
                    for (int kq = 0; kq < 8; ++kq) {
                        const int k0 = kq * 4;
                        float4 b0 = aload4(&dpG[(size_t)(J * BT + c0 + 0) * LSEQ + kg + k0]);
                        float4 b1 = aload4(&dpG[(size_t)(J * BT + c0 + 1) * LSEQ + kg + k0]);
                        float4 b2 = aload4(&dpG[(size_t)(J * BT + c0 + 2) * LSEQ + kg + k0]);
                        float4 b3 = aload4(&dpG[(size_t)(J * BT + c0 + 3) * LSEQ + kg + k0]);
                        #pragma unroll
                        for (int ri = 0; ri < 4; ++ri) {
                            const float* ar = &A[r0 + ri][k0];
                            float ax = ar[0], ay = ar[1], az = ar[2], aw = ar[3];
                            #pragma unroll
                            for (int ci = 0; ci < 4; ++ci) {
                                float4 bv = ci == 0 ? b0 : ci == 1 ? b1 : ci == 2 ? b2 : b3;
                                float mm = fminf(fminf(ax + bv.x, ay + bv.y),
                                                 fminf(az + bv.z, aw + bv.w));
                                r16[ri * 4 + ci] = fminf(r16[ri * 4 + ci], mm);
                            }
                        }
                    }
                }
                for (int z = tid; z < BT * PIT; z += 256) ((float*)cur)[z] = BIGV;
                __syncthreads();
                #pragma unroll
                for (int w = 0; w < 4; ++w) {             // serialized 4-way merge
                    if (wv == w) {
                        #pragma unroll
                        for (int ri = 0; ri < 4; ++ri)
                            #pragma unroll
                            for (int ci = 0; ci < 4; ++ci)
                                cur[r0 + ri][c0 + ci] =
                                    fminf(cur[r0 + ri][c0 + ci], r16[ri * 4 + ci]);
                    }
                    __syncthreads();
                }
            }

            if (wv == 0) {   // wave 0 sweeps (R2-verified term set)
                const int idx = lane >> 1, h = lane & 1;
                for (int sg = -(BT - 1); sg <= BT - 1; ++sg) {
                    const int asg = sg < 0 ? -sg : sg;
                    const int nc = BT - asg;
                    const bool act = idx < nc;
                    const int li = (sg >= 0) ? idx : idx - sg;
                    const int lj = li + sg;
                    const int lic = li < BT ? li : BT - 1;
                    const int ljc = (lj < BT ? (lj >= 0 ? lj : 0) : BT - 1);
                    const int i = I * BT + li, j = J * BT + lj;
                    const float* rowp = (h == 0) ? &rowT[0][lic][0] : &cur[lic][0];
                    const float* colp = (h == 0) ? &cur[1][ljc] : &dTJ[1][ljc];
                    float ev = edge_min32(rowp, colp);
                    float e1 = BIGV, opt0 = 0.f, farv = BIGV;
                    float x0 = BIGV, x1 = BIGV, x2 = BIGV;
                    if (act) {
                        if (h == 0) {
                            e1 = fminf(ev, rowT[0][li][BT - 1] + brow[lj]);
                            opt0 = ((li + 1 < BT) ? cur[li + 1][lj] : brow[lj]) + s_eI[li];
                            farv = cur[li][lj];
                        } else {
                            x0 = ev;
                            x1 = ((lj >= 1) ? cur[li][lj - 1] : prv[li][31]) + s_eJ[lj];
                            float pe = epm[li][lj];
                            if (pe < BIGV) {
                                float inner = (li + 1 < BT)
                                    ? ((lj >= 1) ? cur[li + 1][lj - 1] : prv[li + 1][31])
                                    : ((lj >= 1) ? brow[lj - 1] : bcorn_s);
                                x2 = inner + pe;
                            }
                        }
                    }
                    float y0 = __shfl_xor(x0, 1), y1 = __shfl_xor(x1, 1), y2 = __shfl_xor(x2, 1);
                    if (act && h == 0) {
                        float best = fminf(fminf(fminf(e1, y0), farv), y2);
                        int cch = (best == opt0) ? 0 : (best == y1) ? 1
                                 : (best == y2 && y2 < BIGV) ? 2 : 3;
                        cur[li][lj] = best;
                        astore(&dpG[(size_t)i * LSEQ + j], best);
                        if (i > 0) astore(&dpG[(size_t)j * LSEQ + i - 1], best);
                        choice_write_rel(mask, mb + (size_t)j * LSEQ + i, cch, mmode);
                    }
                }
            }
            asm volatile("s_waitcnt vmcnt(0)" ::: "memory");
            __syncthreads();
            if (tid == 0)
                __hip_atomic_fetch_add(&cnt[s], 1u, __ATOMIC_RELAXED,
                                       __HIP_MEMORY_SCOPE_AGENT);
        }
    }
}

// Traceback (R3-proven): 8 waves stage choices into LDS, wave 0 traverses
// barrier-free with the interval cached in registers.
__global__ __launch_bounds__(512) void tb_kernel(
    const float* __restrict__ e_pair, const void* mask, float* __restrict__ out)
{
    const int b = blockIdx.x;
    const int tid = threadIdx.x;
    const int lane = tid & 63, wv = tid >> 6;
    const float* dp = e_pair + (size_t)b * NN;
    const size_t mb = (size_t)b * NN;
    const int mmode = detect_mmode_wave((const unsigned char*)mask, lane);

    __shared__ __align__(16) unsigned char ch[LSEQ * LSEQ];   // 147456 B
    __shared__ short res[LSEQ];
    __shared__ int st[TB_STK];

    if (mmode == 1) {
        const uint4* src = (const uint4*)((const unsigned char*)mask + mb);
        for (int z = tid; z < (int)(NN / 16); z += 512) ((uint4*)ch)[z] = src[z];
    } else if (mmode == 2) {
        const uint4* src = (const uint4*)((const unsigned char*)mask + mb * 2);
        for (int z = tid; z < (int)(NN / 8); z += 512) {
            uint4 v = src[z];
            unsigned int lo = (v.x & 0xFFu) | (((v.x >> 16) & 0xFFu) << 8)
                            | ((v.y & 0xFFu) << 16) | (((v.y >> 16) & 0xFFu) << 24);
            unsigned int hi = (v.z & 0xFFu) | (((v.z >> 16) & 0xFFu) << 8)
                            | ((v.w & 0xFFu) << 16) | (((v.w >> 16) & 0xFFu) << 24);
            ((unsigned int*)ch)[z * 2] = lo;
            ((unsigned int*)ch)[z * 2 + 1] = hi;
        }
    } else {
        const uint4* src = (const uint4*)((const unsigned char*)mask + mb * 4);
        for (int z = tid; z < (int)(NN / 4); z += 512) {
            uint4 v = src[z];
            ((unsigned int*)ch)[z] = (v.x & 0xFFu) | ((v.y & 0xFFu) << 8)
                                   | ((v.z & 0xFFu) << 16) | ((v.w & 0xFFu) << 24);
        }
    }
    for (int l = tid; l < LSEQ; l += 512) res[l] = -1;
    __syncthreads();
    if (wv != 0) return;   // wave 0 traverses alone

    int sp = 0;
    int ci = 0, cj = LSEQ - 1;
    int have = 1;
    for (int iter = 0; iter < 8192; ++iter) {
        if (!have) {
            if (sp == 0) break;
            --sp;
            int pk = st[sp];
            ci = pk >> 16; cj = pk & 0xFFFF;
        }
        have = 0;
        if (ci >= cj) continue;
        int c = ch[(size_t)cj * LSEQ + ci];
        if (c == 0) { ++ci; have = 1; }
        else if (c == 1) { --cj; have = 1; }
        else if (c == 2) {
            res[ci] = (short)cj; res[cj] = (short)ci;
            if (ci + 1 <= cj - 1) { ++ci; --cj; have = 1; }
        } else {
            const int d = cj - ci;
            const float* rowi = dp + (size_t)ci * LSEQ;
            const float* mrow = dp + (size_t)cj * LSEQ;
            float bv = BIGV; int bt = d;
            for (int t = lane; t < d; t += 64) {
                float cc = rowi[ci + t] + mrow[ci + t];
                if (cc < bv || (cc == bv && t < bt)) { bv = cc; bt = t; }
            }
            for (int m = 32; m > 0; m >>= 1) {
                float ov = __shfl_xor(bv, m, 64);
                int   ot = __shfl_xor(bt, m, 64);
                if (ov < bv || (ov == bv && ot < bt)) { bv = ov; bt = ot; }
            }
            int k = ci + bt;
            if (sp < TB_STK - 1) { st[sp] = ((k + 1) << 16) | cj; ++sp; }
            cj = k; have = 1;   // process (ci, k) next
        }
    }

    for (int l = lane; l < LSEQ; l += 64)
        out[b * LSEQ + l] = (float)res[l];
    if (lane == 0)
        out[BATCH * LSEQ + b] = dp[LSEQ - 1];
}

extern "C" void kernel_launch(void* const* d_in, const int* in_sizes, int n_in,
                              void* d_out, int out_size, void* d_ws, size_t ws_size,
                              hipStream_t stream) {
    float* e_pair = (float*)d_in[0];
    const float* e_unp = (const float*)d_in[1];
    void* mask = d_in[2];
    unsigned int* ws = (unsigned int*)d_ws;
    (void)ws_size;

    init_ws<<<1, 256, 0, stream>>>(ws);
    dp_rows<<<NJOBS, 256, 0, stream>>>(e_pair, e_unp, mask, ws);
    tb_kernel<<<BATCH, 512, 0, stream>>>(e_pair, mask, (float*)d_out);
}

// Round 6
// 775.613 us; speedup vs baseline: 1.1759x; 1.1408x over previous
//
#include <hip/hip_runtime.h>

#define LSEQ 384
#define BATCH 32
#define BIGV 1e30f
#define TB_STK 448
#define NN ((size_t)LSEQ * LSEQ)
#define BT 32          // tile size
#define NT 12          // tiles per side
#define PIT 33         // LDS pitch

__device__ __forceinline__ int detect_mmode_wave(const unsigned char* m0, int lane) {
    unsigned char v = m0[lane & 63];
    unsigned long long big = __ballot(v >= 2);
    unsigned long long off = __ballot((((lane & 63) & 3) != 0) && (v != 0));
    return big ? 2 : (off ? 1 : 0);
}
__device__ __forceinline__ bool mask_read(const void* mask, size_t idx, int mmode) {
    if (mmode == 0) return ((const unsigned int*)mask)[idx] != 0;
    if (mmode == 1) return ((const unsigned char*)mask)[idx] != 0;
    return ((const unsigned short*)mask)[idx] != 0;
}
__device__ __forceinline__ void choice_write(void* mask, size_t idx, int c, int mmode) {
    if (mmode == 0) ((unsigned int*)mask)[idx] = (unsigned int)c;
    else if (mmode == 1) ((unsigned char*)mask)[idx] = (unsigned char)c;
    else ((unsigned short*)mask)[idx] = (unsigned short)c;
}

// Fixed-length branchless edge reduction (R2-verified): min over kk in [0,32)
// of rowp[kk] + colp[kk*PIT]; out-of-range terms >= 1e30 via BIGV prefill ->
// never win or tie -> bitwise identical to the ranged version.
__device__ __forceinline__ float edge_min32(const float* rowp, const float* colp) {
    float a0 = BIGV, a1 = BIGV, a2 = BIGV, a3 = BIGV;
    #pragma unroll
    for (int kk = 0; kk < 32; kk += 4) {
        float r0 = rowp[kk], r1 = rowp[kk + 1], r2 = rowp[kk + 2], r3 = rowp[kk + 3];
        const float* cb = colp + kk * PIT;
        float c0 = cb[0], c1 = cb[PIT], c2 = cb[2 * PIT], c3 = cb[3 * PIT];
        a0 = fminf(a0, r0 + c0); a1 = fminf(a1, r1 + c1);
        a2 = fminf(a2, r2 + c2); a3 = fminf(a3, r3 + c3);
    }
    return fminf(fminf(a0, a1), fminf(a2, a3));
}

// Min-plus of <=2 middle panels, 4-wave split: wave w handles M=fm[w>>1],
// kq range (w&1)*4..+3. Exactly R2's far-init inner loop (term-identical):
// part[r][c] accumulates min_kk dp[i][M*BT+kk] + mirror[j][M*BT+kk]
//          = min_k dp[i][k] + dp[k+1][j] over k in tile M.
__device__ __forceinline__ void minplus_waves(
    const float* __restrict__ dpG, int I, int J, const int* fm, int nfm,
    int wv, int lane, float part[4][BT][PIT])
{
    const int r0 = (lane >> 3) << 2, c0 = (lane & 7) << 2;
    float r16[16];
    #pragma unroll
    for (int z = 0; z < 16; ++z) r16[z] = BIGV;
    const int mi = wv >> 1, kqB = (wv & 1) * 4;
    if (mi < nfm) {
        const int M = fm[mi];
        #pragma unroll
        for (int q = 0; q < 4; ++q) {
            const int k = M * BT + (kqB + q) * 4;
            float4 a0 = *(const float4*)&dpG[(size_t)(I * BT + r0 + 0) * LSEQ + k];
            float4 a1 = *(const float4*)&dpG[(size_t)(I * BT + r0 + 1) * LSEQ + k];
            float4 a2 = *(const float4*)&dpG[(size_t)(I * BT + r0 + 2) * LSEQ + k];
            float4 a3 = *(const float4*)&dpG[(size_t)(I * BT + r0 + 3) * LSEQ + k];
            float4 b0 = *(const float4*)&dpG[(size_t)(J * BT + c0 + 0) * LSEQ + k];
            float4 b1 = *(const float4*)&dpG[(size_t)(J * BT + c0 + 1) * LSEQ + k];
            float4 b2 = *(const float4*)&dpG[(size_t)(J * BT + c0 + 2) * LSEQ + k];
            float4 b3 = *(const float4*)&dpG[(size_t)(J * BT + c0 + 3) * LSEQ + k];
            #pragma unroll
            for (int ri = 0; ri < 4; ++ri) {
                float4 av = ri == 0 ? a0 : ri == 1 ? a1 : ri == 2 ? a2 : a3;
                #pragma unroll
                for (int ci = 0; ci < 4; ++ci) {
                    float4 bv = ci == 0 ? b0 : ci == 1 ? b1 : ci == 2 ? b2 : b3;
                    float m = fminf(fminf(av.x + bv.x, av.y + bv.y),
                                    fminf(av.z + bv.z, av.w + bv.w));
                    r16[ri * 4 + ci] = fminf(r16[ri * 4 + ci], m);
                }
            }
        }
    }
    #pragma unroll
    for (int ri = 0; ri < 4; ++ri)
        #pragma unroll
        for (int ci = 0; ci < 4; ++ci)
            part[wv][r0 + ri][c0 + ci] = r16[ri * 4 + ci];
}

// acc tile base offsets for s>=4 (counts 12-s): 36 tiles per batch.
__device__ __constant__ int c_sb4[12] = {0,0,0,0, 0, 8, 15, 21, 26, 30, 33, 35};

// ---------- phase 0: one block (1 wave) per diagonal tile (R2-proven) ----------
__global__ __launch_bounds__(64) void diag_kernel(
    float* __restrict__ e_pair, const float* __restrict__ e_unp, void* mask)
{
    __shared__ float dT[BT + 1][PIT];   // BIGV-prefilled; row 32 = pad
    __shared__ float epm[BT][PIT];
    __shared__ float s_eunp[BT];

    const int bid = blockIdx.x;
    const int b = bid / NT, t = bid % NT;
    const int lane = threadIdx.x;
    float* dpG = e_pair + (size_t)b * NN;
    const size_t mb = (size_t)b * NN;
    const int mmode = detect_mmode_wave((const unsigned char*)mask, lane);

    for (int z = lane; z < (BT + 1) * PIT; z += 64) ((float*)dT)[z] = BIGV;
    __syncthreads();
    if (lane < BT) {
        int i = t * BT + lane;
        float v = e_unp[b * LSEQ + i];
        s_eunp[lane] = v;
        dT[lane][lane] = v;                            // dp[i][i]
        dpG[(size_t)i * LSEQ + i] = v;
        if (i > 0) dpG[(size_t)i * LSEQ + i - 1] = v;  // mirror
    }
    for (int z = lane; z < BT * BT; z += 64) {         // stage masked energies
        int li = z >> 5, lj = z & 31;
        int i = t * BT + li, j = t * BT + lj;
        bool ok = (lj - li > 4) && mask_read(mask, mb + (size_t)i * LSEQ + j, mmode);
        epm[li][lj] = ok ? dpG[(size_t)i * LSEQ + j] : BIGV;
    }
    __syncthreads();

    const int idx = lane >> 1, h = lane & 1;
    for (int sg = 1; sg < BT; ++sg) {
        const int nc = BT - sg;
        const bool act = idx < nc;
        const int li = idx, lj = idx + sg;
        const int ljc = lj < BT ? lj : BT - 1;
        const int i = t * BT + li, j = t * BT + lj;
        float ev = edge_min32(&dT[li][0], &dT[1][ljc]);
        float e1 = BIGV, opt0 = 0.f, x1 = BIGV, x2 = BIGV;
        if (act) {
            if (h == 0) {
                e1 = ev;                               // includes opt0(kk=li), opt1(kk=lj-1)
                opt0 = dT[li + 1][lj] + s_eunp[li];
            } else {
                x1 = dT[li][lj - 1] + s_eunp[lj];
                float pe = epm[li][lj];
                if (pe < BIGV) x2 = dT[li + 1][lj - 1] + pe;
            }
        }
        float y1 = __shfl_xor(x1, 1), y2 = __shfl_xor(x2, 1);
        if (act && h == 0) {
            float best = fminf(e1, y2);
            int cch = (best == opt0) ? 0 : (best == y1) ? 1
                     : (best == y2 && y2 < BIGV) ? 2 : 3;
            dT[li][lj] = best;
            dpG[(size_t)i * LSEQ + j] = best;
            if (i > 0) dpG[(size_t)j * LSEQ + i - 1] = best;
            choice_write(mask, mb + (size_t)j * LSEQ + i, cch, mmode);
        }
    }
}

// ---------- dispatch p (1..11): sweep blocks (phase-p tiles) + update blocks
// (pre-accumulate far-init pairs for FUTURE tiles into acc).
// Pair (I,J,M) runs at dispatch max(M-I,J-M)+1 <= s-1 -> strictly before the
// tile's sweep dispatch -> no races; first touch writes (no init needed).
__global__ __launch_bounds__(256) void step_kernel(
    float* __restrict__ e_pair, const float* __restrict__ e_unp,
    void* mask, float* __restrict__ acc, int p)
{
    __shared__ float dTI[BT + 1][PIT], dTJ[BT + 1][PIT];
    __shared__ float cur[BT + 1][PIT];
    __shared__ float epm[BT][PIT];
    __shared__ float part[4][BT][PIT];
    __shared__ float brow[BT], bcol[BT], s_eI[BT], s_eJ[BT];
    __shared__ float bcorn;

    const int b = blockIdx.x % BATCH;
    const int u = blockIdx.x / BATCH;
    const int nswp = NT - p;
    const int tid = threadIdx.x, lane = tid & 63, wv = tid >> 6;
    float* dpG = e_pair + (size_t)b * NN;
    const size_t mb = (size_t)b * NN;

    if (u >= nswp) {
        // ---------------- update role ----------------
        int e = u - nswp, s2 = p + 1;
        while (s2 < NT && e >= NT - s2) { e -= NT - s2; ++s2; }
        const int I = e, J = I + s2;
        int fm[2]; fm[0] = I + p - 1; int nfm = 1;
        if (J - (p - 1) != fm[0]) fm[nfm++] = J - (p - 1);
        minplus_waves(dpG, I, J, fm, nfm, wv, lane, part);
        __syncthreads();
        float* accT = acc + ((size_t)(b * 36 + c_sb4[s2] + I) << 10);
        const bool first = (p == (s2 + 1) / 2 + 1);
        for (int z = tid; z < BT * BT; z += 256) {
            int li = z >> 5, lj = z & 31;
            float m = fminf(fminf(part[0][li][lj], part[1][li][lj]),
                            fminf(part[2][li][lj], part[3][li][lj]));
            accT[z] = first ? m : fminf(accT[z], m);
        }
        return;
    }

    // ---------------- sweep role: tile (I, J = I+p) ----------------
    const int I = u, J = I + p, s = p;
    const int mmode = detect_mmode_wave((const unsigned char*)mask, lane);

    for (int z = tid; z < BT * BT; z += 256) {        // diag tiles, lower->BIGV
        int li = z >> 5, lj = z & 31;
        dTI[li][lj] = (lj >= li) ? dpG[(size_t)(I * BT + li) * LSEQ + I * BT + lj] : BIGV;
        dTJ[li][lj] = (lj >= li) ? dpG[(size_t)(J * BT + li) * LSEQ + J * BT + lj] : BIGV;
    }
    for (int z = tid; z < PIT; z += 256) {            // pad rows
        dTI[BT][z] = BIGV; dTJ[BT][z] = BIGV; cur[BT][z] = BIGV;
    }
    if (tid < BT) {
        brow[tid] = dpG[(size_t)((I + 1) * BT) * LSEQ + J * BT + tid];
        s_eI[tid] = e_unp[b * LSEQ + I * BT + tid];
    } else if (tid < 2 * BT) {
        int q = tid - BT;
        bcol[q] = dpG[(size_t)(I * BT + q) * LSEQ + J * BT - 1];
        s_eJ[q] = e_unp[b * LSEQ + J * BT + q];
    } else if (tid == 2 * BT) {
        bcorn = (s >= 2) ? dpG[(size_t)((I + 1) * BT) * LSEQ + J * BT - 1] : BIGV;
    }
    for (int z = tid; z < BT * BT; z += 256) {        // masked energies (own tile)
        int li = z >> 5, lj = z & 31;
        int i = I * BT + li, j = J * BT + lj;
        bool ok = (j - i > 4) && mask_read(mask, mb + (size_t)i * LSEQ + j, mmode);
        epm[li][lj] = ok ? dpG[(size_t)i * LSEQ + j] : BIGV;
    }

    // fresh far-init pairs: M = I+1 (s>=2) and M = J-1 (s>=3); pairs with
    // M in [I+2, J-2] (s>=4) come pre-accumulated from acc.
    int fm[2]; int nfm = 0;
    if (s >= 2) fm[nfm++] = I + 1;
    if (s >= 3) fm[nfm++] = J - 1;
    minplus_waves(dpG, I, J, fm, nfm, wv, lane, part);
    __syncthreads();

    const float* accT = acc + ((size_t)(b * 36 + c_sb4[s] + I) << 10);
    for (int z = tid; z < BT * BT; z += 256) {
        int li = z >> 5, lj = z & 31;
        float m = fminf(fminf(part[0][li][lj], part[1][li][lj]),
                        fminf(part[2][li][lj], part[3][li][lj]));
        if (s >= 4) m = fminf(m, accT[z]);
        cur[li][lj] = m;
    }
    __syncthreads();
    if (wv != 0) return;   // wave 0 sweeps with an unshared SIMD

    const int idx = lane >> 1, h = lane & 1;
    for (int sg = -(BT - 1); sg <= BT - 1; ++sg) {
        const int asg = sg < 0 ? -sg : sg;
        const int nc = BT - asg;
        const bool act = idx < nc;
        const int li = (sg >= 0) ? idx : idx - sg;
        const int lj = li + sg;
        const int lic = li < BT ? li : BT - 1;
        const int ljc = (lj < BT ? (lj >= 0 ? lj : 0) : BT - 1);
        const int i = I * BT + li, j = J * BT + lj;
        const float* rowp = (h == 0) ? &dTI[lic][0] : &cur[lic][0];
        const float* colp = (h == 0) ? &cur[1][ljc] : &dTJ[1][ljc];
        float ev = edge_min32(rowp, colp);
        float e1 = BIGV, opt0 = 0.f, farv = BIGV;
        float x0 = BIGV, x1 = BIGV, x2 = BIGV;
        if (act) {
            if (h == 0) {
                e1 = fminf(ev, dTI[li][BT - 1] + brow[lj]);
                opt0 = ((li + 1 < BT) ? cur[li + 1][lj] : brow[lj]) + s_eI[li];
                farv = cur[li][lj];
            } else {
                x0 = ev;
                x1 = ((lj >= 1) ? cur[li][lj - 1] : bcol[li]) + s_eJ[lj];
                float pe = epm[li][lj];
                if (pe < BIGV) {
                    float inner = (li + 1 < BT)
                        ? ((lj >= 1) ? cur[li + 1][lj - 1] : bcol[li + 1])
                        : ((lj >= 1) ? brow[lj - 1] : bcorn);
                    x2 = inner + pe;
                }
            }
        }
        float y0 = __shfl_xor(x0, 1), y1 = __shfl_xor(x1, 1), y2 = __shfl_xor(x2, 1);
        if (act && h == 0) {
            float best = fminf(fminf(fminf(e1, y0), farv), y2);
            int cch = (best == opt0) ? 0 : (best == y1) ? 1
                     : (best == y2 && y2 < BIGV) ? 2 : 3;
            cur[li][lj] = best;
            dpG[(size_t)i * LSEQ + j] = best;
            if (i > 0) dpG[(size_t)j * LSEQ + i - 1] = best;
            choice_write(mask, mb + (size_t)j * LSEQ + i, cch, mmode);
        }
    }
}

// Traceback (R3-proven): 8 waves stage choices into LDS, wave 0 traverses
// barrier-free with the interval cached in registers.
__global__ __launch_bounds__(512) void tb_kernel(
    const float* __restrict__ e_pair, const void* mask, float* __restrict__ out)
{
    const int b = blockIdx.x;
    const int tid = threadIdx.x;
    const int lane = tid & 63, wv = tid >> 6;
    const float* dp = e_pair + (size_t)b * NN;
    const size_t mb = (size_t)b * NN;
    const int mmode = detect_mmode_wave((const unsigned char*)mask, lane);

    __shared__ __align__(16) unsigned char ch[LSEQ * LSEQ];   // 147456 B
    __shared__ short res[LSEQ];
    __shared__ int st[TB_STK];

    if (mmode == 1) {
        const uint4* src = (const uint4*)((const unsigned char*)mask + mb);
        for (int z = tid; z < (int)(NN / 16); z += 512) ((uint4*)ch)[z] = src[z];
    } else if (mmode == 2) {
        const uint4* src = (const uint4*)((const unsigned char*)mask + mb * 2);
        for (int z = tid; z < (int)(NN / 8); z += 512) {
            uint4 v = src[z];
            unsigned int lo = (v.x & 0xFFu) | (((v.x >> 16) & 0xFFu) << 8)
                            | ((v.y & 0xFFu) << 16) | (((v.y >> 16) & 0xFFu) << 24);
            unsigned int hi = (v.z & 0xFFu) | (((v.z >> 16) & 0xFFu) << 8)
                            | ((v.w & 0xFFu) << 16) | (((v.w >> 16) & 0xFFu) << 24);
            ((unsigned int*)ch)[z * 2] = lo;
            ((unsigned int*)ch)[z * 2 + 1] = hi;
        }
    } else {
        const uint4* src = (const uint4*)((const unsigned char*)mask + mb * 4);
        for (int z = tid; z < (int)(NN / 4); z += 512) {
            uint4 v = src[z];
            ((unsigned int*)ch)[z] = (v.x & 0xFFu) | ((v.y & 0xFFu) << 8)
                                   | ((v.z & 0xFFu) << 16) | ((v.w & 0xFFu) << 24);
        }
    }
    for (int l = tid; l < LSEQ; l += 512) res[l] = -1;
    __syncthreads();
    if (wv != 0) return;   // wave 0 traverses alone

    int sp = 0;
    int ci = 0, cj = LSEQ - 1;
    int have = 1;
    for (int iter = 0; iter < 8192; ++iter) {
        if (!have) {
            if (sp == 0) break;
            --sp;
            int pk = st[sp];
            ci = pk >> 16; cj = pk & 0xFFFF;
        }
        have = 0;
        if (ci >= cj) continue;
        int c = ch[(size_t)cj * LSEQ + ci];
        if (c == 0) { ++ci; have = 1; }
        else if (c == 1) { --cj; have = 1; }
        else if (c == 2) {
            res[ci] = (short)cj; res[cj] = (short)ci;
            if (ci + 1 <= cj - 1) { ++ci; --cj; have = 1; }
        } else {
            const int d = cj - ci;
            const float* rowi = dp + (size_t)ci * LSEQ;
            const float* mrow = dp + (size_t)cj * LSEQ;
            float bv = BIGV; int bt = d;
            for (int t = lane; t < d; t += 64) {
                float cc = rowi[ci + t] + mrow[ci + t];
                if (cc < bv || (cc == bv && t < bt)) { bv = cc; bt = t; }
            }
            for (int m = 32; m > 0; m >>= 1) {
                float ov = __shfl_xor(bv, m, 64);
                int   ot = __shfl_xor(bt, m, 64);
                if (ov < bv || (ov == bv && ot < bt)) { bv = ov; bt = ot; }
            }
            int k = ci + bt;
            if (sp < TB_STK - 1) { st[sp] = ((k + 1) << 16) | cj; ++sp; }
            cj = k; have = 1;   // process (ci, k) next
        }
    }

    for (int l = lane; l < LSEQ; l += 64)
        out[b * LSEQ + l] = (float)res[l];
    if (lane == 0)
        out[BATCH * LSEQ + b] = dp[LSEQ - 1];
}

extern "C" void kernel_launch(void* const* d_in, const int* in_sizes, int n_in,
                              void* d_out, int out_size, void* d_ws, size_t ws_size,
                              hipStream_t stream) {
    float* e_pair = (float*)d_in[0];
    const float* e_unp = (const float*)d_in[1];
    void* mask = d_in[2];
    float* acc = (float*)d_ws;   // 32 batches x 36 tiles x 1024 floats = 4.72 MB
    (void)ws_size;

    // update-block counts per dispatch p: tiles with p+1 <= s <= min(2p-2,11)
    static const int updC[12] = {0, 0, 0, 8, 13, 15, 14, 10, 6, 3, 1, 0};

    diag_kernel<<<BATCH * NT, 64, 0, stream>>>(e_pair, e_unp, mask);
    for (int p = 1; p < NT; ++p)
        step_kernel<<<BATCH * (NT - p + updC[p]), 256, 0, stream>>>(
            e_pair, e_unp, mask, acc, p);
    tb_kernel<<<BATCH, 512, 0, stream>>>(e_pair, mask, (float*)d_out);
}